// Round 4
// baseline (708.180 us; speedup 1.0000x reference)
//
#include <hip/hip_runtime.h>
#include <hip/hip_bf16.h>

#define NN 10000
#define NE 50000
#define FIN 40
#define FE 10
// L = 64

typedef float f32x4 __attribute__((ext_vector_type(4)));
typedef short s16x8 __attribute__((ext_vector_type(8)));

__device__ __forceinline__ float bcast(float v, int lane) {
    return __uint_as_float(__builtin_amdgcn_readlane(__float_as_uint(v), lane));
}
__device__ __forceinline__ ushort f2bf(float f) {
    uint u = __float_as_uint(f);
    uint r = (u + 0x7FFFu + ((u >> 16) & 1u)) >> 16;
    return (ushort)r;
}
__device__ __forceinline__ float bf2f(ushort h) {
    return __uint_as_float(((uint)h) << 16);
}

// ---------------- CSR build ----------------
__global__ void k_count(const int* __restrict__ ei, int* __restrict__ deg) {
    int e = blockIdx.x * 256 + threadIdx.x;
    if (e < NE) atomicAdd(&deg[ei[NE + e]], 1);
}

__global__ __launch_bounds__(1024) void k_scan(const int* __restrict__ deg,
                                               int* __restrict__ rowp,
                                               int* __restrict__ fill,
                                               float* __restrict__ invd) {
    __shared__ int wsum[16];
    __shared__ int chunkbase;
    int tid = threadIdx.x, lane = tid & 63, wv = tid >> 6;
    if (tid == 0) chunkbase = 0;
    __syncthreads();
    for (int base = 0; base < NN; base += 1024) {
        int idx = base + tid;
        int v = (idx < NN) ? deg[idx] : 0;
        int s = v;
#pragma unroll
        for (int off = 1; off < 64; off <<= 1) {
            int t = __shfl_up(s, off, 64);
            if (lane >= off) s += t;
        }
        if (lane == 63) wsum[wv] = s;
        __syncthreads();
        int carry = chunkbase;
        if (wv == 0 && lane < 16) {
            int x = wsum[lane];
#pragma unroll
            for (int off = 1; off < 16; off <<= 1) {
                int t = __shfl_up(x, off, 64);
                if (lane >= off) x += t;
            }
            wsum[lane] = x;  // inclusive over waves
        }
        __syncthreads();
        int wpre = (wv == 0) ? 0 : wsum[wv - 1];
        int incl = carry + wpre + s;
        if (idx < NN) {
            rowp[idx] = incl - v;
            fill[idx] = incl - v;
            invd[idx] = 1.0f / (float)(v > 0 ? v : 1);
        }
        __syncthreads();
        if (tid == 0) chunkbase = carry + wsum[15];
        __syncthreads();
    }
    if (tid == 0) rowp[NN] = NE;
}

__global__ void k_fill(const int* __restrict__ ei, int* __restrict__ fill,
                       int* __restrict__ csrs, int* __restrict__ csre) {
    int e = blockIdx.x * 256 + threadIdx.x;
    if (e < NE) {
        int d = ei[NE + e];
        int p = atomicAdd(&fill[d], 1);
        csrs[p] = ei[e];
        csre[p] = e;
    }
}

// ---------------- W2 split-bf16, transposed to [o][ki] (ki = k*64+i) ----------------
__global__ __launch_bounds__(256) void k_w2f(const float* __restrict__ n2w,
                                             ushort* __restrict__ W2FH,
                                             ushort* __restrict__ W2FL) {
    int lane = threadIdx.x & 63, wvl = threadIdx.x >> 6;
    int ki = blockIdx.x * 4 + wvl;
    float v = n2w[(size_t)ki * 64 + lane];
    ushort hi = f2bf(v);
    ushort lo = f2bf(v - bf2f(hi));
    W2FH[(size_t)lane * 4096 + ki] = hi;
    W2FL[(size_t)lane * 4096 + ki] = lo;
}

// ---------------- edge MLP: hE = relu(edge_attr @ nn1_w + nn1_b) ----------------
__global__ __launch_bounds__(256) void k_edge_h(const float* __restrict__ ea,
                                                const float* __restrict__ w1,
                                                const float* __restrict__ b1,
                                                float* __restrict__ hE) {
    int lane = threadIdx.x & 63, wv = threadIdx.x >> 6;
    int e = blockIdx.x * 4 + wv;
    float av = (lane < FE) ? ea[e * FE + lane] : 0.f;
    float acc = b1[lane];
#pragma unroll
    for (int j = 0; j < FE; ++j) acc += bcast(av, j) * w1[j * 64 + lane];
    hE[e * 64 + lane] = fmaxf(acc, 0.f);
}

// ---------------- lin0 ----------------
__global__ __launch_bounds__(256) void k_lin0(const float* __restrict__ x,
                                              const float* __restrict__ w0,
                                              const float* __restrict__ b0,
                                              float* __restrict__ F) {
    int lane = threadIdx.x & 63, wv = threadIdx.x >> 6;
    int n = blockIdx.x * 4 + wv;
    float xv = (lane < FIN) ? x[n * FIN + lane] : 0.f;
    float acc = b0[lane];
#pragma unroll
    for (int k = 0; k < FIN; ++k) acc += bcast(xv, k) * w0[k * 64 + lane];
    F[n * 64 + lane] = fmaxf(acc, 0.f);
}

// ---------------- fused NNConv + GRU via MFMA (split bf16) ----------------
// 8 waves = 8 dst nodes per block (512 thr, launch_bounds(512,4) -> <=128 VGPR,
// no G[] spill, 2 blocks/CU). Phase A: G[k][i] in 64 VGPRs (lane=i).
// 4 k-chunks: convert->LDS(bf16 hi/lo), MFMA 16x16x32; wave=(otile=wv&3,
// kq=wv>>2 in {0,1}); A rows 8..15 fed zeros. Reduce over kq via LDS.
// Epilogue: mean + root + relu -> m, then GRU -> Fout (ping-pong).
__global__ __launch_bounds__(512, 4) void k_mp(
    const float* __restrict__ F, const float* __restrict__ hE,
    const int* __restrict__ rowp, const int* __restrict__ csrs,
    const int* __restrict__ csre,
    const ushort* __restrict__ W2FH, const ushort* __restrict__ W2FL,
    const float* __restrict__ B2, const float* __restrict__ invd,
    const float* __restrict__ Wroot, const float* __restrict__ broot,
    const float* __restrict__ Wih, const float* __restrict__ Whh,
    const float* __restrict__ bih, const float* __restrict__ bhh,
    float* __restrict__ Fout) {
    __shared__ __align__(16) char smem[35072];
    ushort(*GH)[1032] = (ushort(*)[1032])smem;             // 8*2064 = 16512 B
    ushort(*GL)[1032] = (ushort(*)[1032])(smem + 16512);   // 16512 B
    float(*Us)[64] = (float(*)[64])(smem + 33024);         // 2048 B
    float(*Red)[256] = (float(*)[256])smem;                // union over GH (8 KB)
    float(*Agg)[64] = (float(*)[64])(smem + 16512);        // union over GL (2 KB)

    int tid = threadIdx.x, lane = tid & 63, wv = tid >> 6;
    int n = __builtin_amdgcn_readfirstlane(blockIdx.x * 8 + wv);

    // ---- phase A: G[k][i] = sum_e hE[e][k] * F[src][i]; lane = i ----
    float G[64];
#pragma unroll
    for (int k = 0; k < 64; ++k) G[k] = 0.f;
    float usum = 0.f;
    int beg = rowp[n], end = rowp[n + 1];
    for (int p = beg; p < end; ++p) {
        int s = __builtin_amdgcn_readfirstlane(csrs[p]);
        int e = __builtin_amdgcn_readfirstlane(csre[p]);
        float u = F[(size_t)s * 64 + lane];
        const float* h = hE + (size_t)e * 64;  // uniform -> s_load
        usum += u;
#pragma unroll
        for (int k = 0; k < 64; ++k) G[k] = fmaf(h[k], u, G[k]);
    }
    Us[wv][lane] = usum;

    // ---- MFMA phase ----
    f32x4 acc = {0.f, 0.f, 0.f, 0.f};
    int otile = wv & 3, kq = wv >> 2;  // kq in {0,1}
    int arow = lane & 15, agrp = lane >> 4;
    int o = otile * 16 + arow;
    const ushort* bhbase = W2FH + (size_t)o * 4096;
    const ushort* blbase = W2FL + (size_t)o * 4096;
#pragma unroll
    for (int c = 0; c < 4; ++c) {
#pragma unroll
        for (int kk = 0; kk < 16; ++kk) {
            float g = G[c * 16 + kk];
            ushort hi = f2bf(g);
            ushort lo = f2bf(g - bf2f(hi));
            GH[wv][kk * 64 + lane] = hi;
            GL[wv][kk * 64 + lane] = lo;
        }
        __syncthreads();
#pragma unroll
        for (int s8 = 0; s8 < 16; ++s8) {
            int ki = (kq * 16 + s8) * 32 + agrp * 8;
            s16x8 ah = {0, 0, 0, 0, 0, 0, 0, 0};
            s16x8 al = {0, 0, 0, 0, 0, 0, 0, 0};
            if (arow < 8) {
                ah = *(const s16x8*)&GH[arow][ki];
                al = *(const s16x8*)&GL[arow][ki];
            }
            s16x8 bh = *(const s16x8*)&bhbase[c * 1024 + ki];
            s16x8 bl = *(const s16x8*)&blbase[c * 1024 + ki];
            acc = __builtin_amdgcn_mfma_f32_16x16x32_bf16(ah, bh, acc, 0, 0, 0);
            acc = __builtin_amdgcn_mfma_f32_16x16x32_bf16(ah, bl, acc, 0, 0, 0);
            acc = __builtin_amdgcn_mfma_f32_16x16x32_bf16(al, bh, acc, 0, 0, 0);
        }
        __syncthreads();
    }

    // ---- reduce partial D over the 2 kq groups ----
    *(f32x4*)&Red[wv][lane * 4] = acc;
    __syncthreads();
    if (wv < 4) {
        int t = wv;
        f32x4 s0 = *(f32x4*)&Red[t][lane * 4];
        f32x4 s1 = *(f32x4*)&Red[t + 4][lane * 4];
        f32x4 ss = s0 + s1;
        // D[row=node=(lane>>4)*4+r][col=o=t*16+(lane&15)]; rows >=8 are zero/unused
#pragma unroll
        for (int r = 0; r < 4; ++r) {
            int row = (lane >> 4) * 4 + r;
            if (row < 8) Agg[row][t * 16 + (lane & 15)] = ss[r];
        }
    }
    __syncthreads();

    // ---- epilogue per node-wave: mean + nn2_b + root -> relu -> m ----
    float b2t = 0.f;
#pragma unroll 8
    for (int i = 0; i < 64; ++i) b2t = fmaf(Us[wv][i], B2[i * 64 + lane], b2t);
    float a = (Agg[wv][lane] + b2t) * invd[n];
    const float* frow = F + (size_t)n * 64;  // uniform -> s_load
    float r = broot[lane];
#pragma unroll
    for (int k = 0; k < 64; ++k) r = fmaf(frow[k], Wroot[k * 64 + lane], r);
    float m = fmaxf(a + r, 0.f);

    // ---- fused single-step GRU: h' = (1-z)*ng + z*h ----
    float h = F[(size_t)n * 64 + lane];
    float sr = bih[lane] + bhh[lane];
    float sz = bih[64 + lane] + bhh[64 + lane];
    float gin = bih[128 + lane];
    float ghn = bhh[128 + lane];
#pragma unroll
    for (int k = 0; k < 64; ++k) {
        float mk = bcast(m, k), hk = bcast(h, k);
        const float* wi = &Wih[k * 192];
        const float* wh = &Whh[k * 192];
        sr = fmaf(mk, wi[lane], fmaf(hk, wh[lane], sr));
        sz = fmaf(mk, wi[64 + lane], fmaf(hk, wh[64 + lane], sz));
        gin = fmaf(mk, wi[128 + lane], gin);
        ghn = fmaf(hk, wh[128 + lane], ghn);
    }
    float rr = 1.f / (1.f + __expf(-sr));
    float zz = 1.f / (1.f + __expf(-sz));
    float ng = tanhf(gin + rr * ghn);
    Fout[(size_t)n * 64 + lane] = (1.f - zz) * ng + zz * h;
}

// ---------------- final ----------------
__global__ __launch_bounds__(256) void k_final(const float* __restrict__ F,
                                               const float* __restrict__ W1,
                                               const float* __restrict__ b1f,
                                               const float* __restrict__ W2l,
                                               const float* __restrict__ b2f,
                                               float* __restrict__ out) {
    int lane = threadIdx.x & 63, wv = threadIdx.x >> 6;
    int n = blockIdx.x * 4 + wv;
    float fv = F[n * 64 + lane];
    float acc = b1f[lane];
#pragma unroll
    for (int k = 0; k < 64; ++k) acc += bcast(fv, k) * W1[k * 64 + lane];
    acc = fmaxf(acc, 0.f);
    float p = acc * W2l[lane];
#pragma unroll
    for (int off = 32; off; off >>= 1) p += __shfl_xor(p, off, 64);
    if (lane == 0) out[n] = p + b2f[0];
}

extern "C" void kernel_launch(void* const* d_in, const int* in_sizes, int n_in,
                              void* d_out, int out_size, void* d_ws, size_t ws_size,
                              hipStream_t stream) {
    const float* x = (const float*)d_in[0];
    const int* ei = (const int*)d_in[1];
    const float* ea = (const float*)d_in[2];
    const float* l0w = (const float*)d_in[3];
    const float* l0b = (const float*)d_in[4];
    const float* n1w = (const float*)d_in[5];
    const float* n1b = (const float*)d_in[6];
    const float* n2w = (const float*)d_in[7];
    const float* n2b = (const float*)d_in[8];
    const float* cr = (const float*)d_in[9];
    const float* cb = (const float*)d_in[10];
    const float* wih = (const float*)d_in[11];
    const float* whh = (const float*)d_in[12];
    const float* bih = (const float*)d_in[13];
    const float* bhh = (const float*)d_in[14];
    const float* l1w = (const float*)d_in[15];
    const float* l1b = (const float*)d_in[16];
    const float* l2w = (const float*)d_in[17];
    const float* l2b = (const float*)d_in[18];

    char* w = (char*)d_ws;
    size_t off = 0;
    float* F0 = (float*)(w + off); off += (size_t)NN * 64 * 4;
    float* F1 = (float*)(w + off); off += (size_t)NN * 64 * 4;
    float* hE = (float*)(w + off); off += (size_t)NE * 64 * 4;
    ushort* W2FH = (ushort*)(w + off); off += (size_t)64 * 4096 * 2;
    ushort* W2FL = (ushort*)(w + off); off += (size_t)64 * 4096 * 2;
    float* invd = (float*)(w + off); off += (size_t)NN * 4;
    int* deg = (int*)(w + off); off += (size_t)NN * 4;
    int* rowp = (int*)(w + off); off += (size_t)(NN + 1) * 4 + 252; off &= ~(size_t)255;
    int* fill = (int*)(w + off); off += (size_t)NN * 4;
    int* csrs = (int*)(w + off); off += (size_t)NE * 4;
    int* csre = (int*)(w + off); off += (size_t)NE * 4;

    hipMemsetAsync(deg, 0, NN * 4, stream);
    k_count<<<(NE + 255) / 256, 256, 0, stream>>>(ei, deg);
    k_scan<<<1, 1024, 0, stream>>>(deg, rowp, fill, invd);
    k_fill<<<(NE + 255) / 256, 256, 0, stream>>>(ei, fill, csrs, csre);
    k_w2f<<<1024, 256, 0, stream>>>(n2w, W2FH, W2FL);
    k_edge_h<<<NE / 4, 256, 0, stream>>>(ea, n1w, n1b, hE);
    k_lin0<<<NN / 4, 256, 0, stream>>>(x, l0w, l0b, F0);
    float* Fcur = F0;
    float* Fnxt = F1;
    for (int it = 0; it < 3; ++it) {
        k_mp<<<NN / 8, 512, 0, stream>>>(Fcur, hE, rowp, csrs, csre, W2FH,
                                         W2FL, n2b, invd, cr, cb, wih, whh,
                                         bih, bhh, Fnxt);
        float* t = Fcur; Fcur = Fnxt; Fnxt = t;
    }
    k_final<<<NN / 4, 256, 0, stream>>>(Fcur, l1w, l1b, l2w, l2b, (float*)d_out);
}